// Round 3
// baseline (2264.288 us; speedup 1.0000x reference)
//
#include <hip/hip_runtime.h>
#include <math.h>

#define NH 16
#define HD 128
#define CH1 2048
#define CH3 6144
#define CK 64
#define NC 128
#define PCH 132   // LDS pitch for 64x128 tensors (bank-friendly, 16B-aligned rows)
#define MP 68     // LDS pitch for 64x64 M / N^T

// workspace layout (float offsets)
#define QT_OFF  0u            // tiled q~   [2048 ch][8g][64t][16d]
#define KBT_OFF 16777216u     // kbar^T     [2048 ch][128k][64t]
#define U0_OFF  33554432u     // U0 natural [8192 t][16 h][128 d]
#define Z_OFF   50331648u     // tiled Z    [2048 ch][8g][64t][16d]
#define W_OFF   67108864u     // tiled W    [2048 ch][8g][64t][8s]
#define ECG_OFF 75497472u     // e^{cg63}   [2048 ch][128 k]
#define SLAB_OFF 75759616u    // (unused by scan3; kept for layout stability)

// ---------------------------------------------------------------------------
// Kernel A: per-(chunk, head) fully parallel. conv+silu+l2norm+gates, then
// A/W pair-matrices (per-pair exponents, always <=0), (I+B A)^-1, Z, U0.
// (unchanged this round)
// ---------------------------------------------------------------------------
__global__ __launch_bounds__(512, 2)
void kda_chunk(const float* __restrict__ mixed, const float* __restrict__ fg,
               const float* __restrict__ beta, const float* __restrict__ cw,
               const float* __restrict__ dtb, const float* __restrict__ alog,
               float* __restrict__ qt_g, float* __restrict__ kbt_g,
               float* __restrict__ u0_g, float* __restrict__ z_g,
               float* __restrict__ w_g, float* __restrict__ ecg_g) {
  __shared__ float lds[35520];
  float* kL  = lds;            // [64][132]
  float* qL  = lds + 8448;     // [64][132], later RHS
  float* cgL = lds + 16896;    // [64][132]
  float* ML  = lds + 25344;    // [64][68]
  float* NT  = lds + 29696;    // [64][68]  (N transposed: NT[col][row])
  float* GB  = lds + 34048;    // [768]
  float* bL  = lds + 34816;    // [64]
  float* nrm = lds + 34880;    // [640]

  const int tid = threadIdx.x;
  const int bid = blockIdx.x;
  const int c = bid >> 4, h = bid & 15;
  const int t0 = c * CK;
  const float ea = __expf(alog[h]);

  // W zero-fill (store-before-barrier ordering makes later overwrites safe)
  {
    size_t wb = (size_t)bid * 4096;
#pragma unroll
    for (int i = 0; i < 8; ++i) w_g[wb + tid + 512 * i] = 0.f;
  }

  // (a) g = -exp(alog)*softplus(fg+dtb) -> cgL
  for (int it = 0; it < 16; ++it) {
    int cell = tid + (it << 9);
    int d = cell & 127, t = cell >> 7;
    float x = fg[(size_t)(t0 + t) * CH1 + h * HD + d] + dtb[h * HD + d];
    float sp = (x > 20.f) ? x : log1pf(__expf(x));
    cgL[t * PCH + d] = -ea * sp;
  }
  if (tid < 64) bL[tid] = 1.f / (1.f + __expf(-beta[(size_t)(t0 + tid) * NH + h]));
  __syncthreads();

  // inclusive prefix over t (per dim) + ecg writeout
  if (tid < 128) {
    float a = 0.f;
    for (int t = 0; t < 64; ++t) { a += cgL[t * PCH + tid]; cgL[t * PCH + tid] = a; }
    ecg_g[(size_t)bid * 128 + tid] = __expf(a);
  }

  // (b) conv+silu for q (sec0) and k (sec1)
  for (int it = 0; it < 32; ++it) {
    int cell = tid + (it << 9);
    int d = cell & 127, sec = (cell >> 7) & 1, t = cell >> 8;
    int ch = sec * CH1 + h * HD + d;
    float4 w4 = ((const float4*)cw)[ch];
    int rbase = t0 + t - 3;
    float acc;
    if (rbase >= 0) {
      const float* mp = mixed + (size_t)rbase * CH3 + ch;
      acc = mp[0] * w4.x + mp[CH3] * w4.y + mp[2 * CH3] * w4.z + mp[3 * CH3] * w4.w;
    } else {
      acc = 0.f;
      if (rbase + 0 >= 0) acc += mixed[(size_t)(rbase + 0) * CH3 + ch] * w4.x;
      if (rbase + 1 >= 0) acc += mixed[(size_t)(rbase + 1) * CH3 + ch] * w4.y;
      if (rbase + 2 >= 0) acc += mixed[(size_t)(rbase + 2) * CH3 + ch] * w4.z;
      acc += mixed[(size_t)(rbase + 3) * CH3 + ch] * w4.w;
    }
    acc = acc / (1.f + __expf(-acc));
    float* dst = (sec == 0) ? qL : kL;
    dst[t * PCH + d] = acc;
  }
  __syncthreads();

  // l2norm partials
  {
    int sec = tid >> 8, t = (tid >> 2) & 63, r = tid & 3;
    const float* src = (sec == 0) ? qL : kL;
    float s = 0.f;
#pragma unroll
    for (int i = 0; i < 8; ++i) {
      float4 v = *(const float4*)(src + t * PCH + r * 32 + i * 4);
      s += v.x * v.x + v.y * v.y + v.z * v.z + v.w * v.w;
    }
    nrm[tid] = s;
  }
  __syncthreads();
  if (tid < 128) {
    int sec = tid >> 6, t = tid & 63;
    float s = nrm[sec * 256 + t * 4] + nrm[sec * 256 + t * 4 + 1] +
              nrm[sec * 256 + t * 4 + 2] + nrm[sec * 256 + t * 4 + 3];
    float inv = rsqrtf(s + 1e-6f);
    if (sec == 0) inv *= 0.08838834764831845f;  // q scale D^-0.5
    nrm[512 + tid] = inv;
  }
  __syncthreads();
  for (int it = 0; it < 8; ++it) {
    int f4 = tid + (it << 9);
    int sec = f4 >> 11, t = (f4 >> 5) & 63, d4 = f4 & 31;
    float* dst = (sec == 0) ? qL : kL;
    float inv = nrm[512 + sec * 64 + t];
    float4 v = *(float4*)(dst + t * PCH + d4 * 4);
    v.x *= inv; v.y *= inv; v.z *= inv; v.w *= inv;
    *(float4*)(dst + t * PCH + d4 * 4) = v;
  }
  __syncthreads();

  // (c) writeouts: q~ (tiled), kbar^T
  {
    int tW = tid >> 3, g = tid & 7;
    size_t qb = (size_t)bid * 8192 + g * 1024 + tW * 16;
    size_t kb = (size_t)bid * 8192;
#pragma unroll
    for (int i = 0; i < 4; ++i) {
      int d = g * 16 + 4 * i;
      float4 qv = *(const float4*)(qL + tW * PCH + d);
      float4 cg4 = *(const float4*)(cgL + tW * PCH + d);
      float4 o;
      o.x = qv.x * __expf(cg4.x); o.y = qv.y * __expf(cg4.y);
      o.z = qv.z * __expf(cg4.z); o.w = qv.w * __expf(cg4.w);
      *(float4*)(qt_g + qb + 4 * i) = o;
      float4 kv = *(const float4*)(kL + tW * PCH + d);
      float4 c63 = *(const float4*)(cgL + 63 * PCH + d);
      kbt_g[kb + (size_t)(d + 0) * 64 + tW] = kv.x * __expf(c63.x - cg4.x);
      kbt_g[kb + (size_t)(d + 1) * 64 + tW] = kv.y * __expf(c63.y - cg4.y);
      kbt_g[kb + (size_t)(d + 2) * 64 + tW] = kv.z * __expf(c63.z - cg4.z);
      kbt_g[kb + (size_t)(d + 3) * 64 + tW] = kv.w * __expf(c63.w - cg4.w);
    }
  }

  // (d) pair-work: A (strict lower, scaled by b -> M) and W (incl lower)
  if (tid < 136) {
    int L = tid;
    int tt = (int)((sqrtf(8.f * L + 1.f) - 1.f) * 0.5f);
    while ((tt + 1) * (tt + 2) / 2 <= L) ++tt;
    while (tt * (tt + 1) / 2 > L) --tt;
    int ss = L - tt * (tt + 1) / 2;
    int ta = tt * 4, sa = ss * 4;
    float accA[16], accW[16];
#pragma unroll
    for (int i = 0; i < 16; ++i) { accA[i] = 0.f; accW[i] = 0.f; }
    for (int d = 0; d < 128; d += 4) {
      float kt[4][4], qt4[4][4], ct[4][4], ks4[4][4], cs4[4][4];
#pragma unroll
      for (int i = 0; i < 4; ++i) {
        *(float4*)kt[i]  = *(const float4*)(kL + (ta + i) * PCH + d);
        *(float4*)qt4[i] = *(const float4*)(qL + (ta + i) * PCH + d);
        *(float4*)ct[i]  = *(const float4*)(cgL + (ta + i) * PCH + d);
        *(float4*)ks4[i] = *(const float4*)(kL + (sa + i) * PCH + d);
        *(float4*)cs4[i] = *(const float4*)(cgL + (sa + i) * PCH + d);
      }
#pragma unroll
      for (int i = 0; i < 4; ++i)
#pragma unroll
        for (int j = 0; j < 4; ++j)
#pragma unroll
          for (int dd = 0; dd < 4; ++dd) {
            float diff = ct[i][dd] - cs4[j][dd];
            float e = __expf(fminf(diff, 0.f));
            float m = e * ks4[j][dd];
            accA[i * 4 + j] += kt[i][dd] * m;
            accW[i * 4 + j] += qt4[i][dd] * m;
          }
    }
    size_t wb = (size_t)bid * 4096;
#pragma unroll
    for (int i = 0; i < 4; ++i)
#pragma unroll
      for (int j = 0; j < 4; ++j) {
        int t = ta + i, s = sa + j;
        if (s < t) ML[t * MP + s] = bL[t] * accA[i * 4 + j];
        float wv = (s <= t) ? accW[i * 4 + j] : 0.f;
        w_g[wb + (size_t)(s >> 3) * 512 + t * 8 + (s & 7)] = wv;
      }
  }
  __syncthreads();

  // (e) N = (I + B A)^-1, stored transposed in NT
  for (int i = tid; i < 4352; i += 512) NT[i] = 0.f;
  __syncthreads();
  if (tid < 64) {
    int b4 = tid >> 4, j = tid & 15, bo = b4 * 16;
    NT[(bo + j) * MP + bo + j] = 1.f;
    for (int t = j + 1; t < 16; ++t) {
      float s = 0.f;
      for (int sx = j; sx < t; ++sx)
        s += ML[(bo + t) * MP + bo + sx] * NT[(bo + j) * MP + bo + sx];
      NT[(bo + j) * MP + bo + t] = -s;
    }
  }
  __syncthreads();
  for (int lev = 1; lev <= 3; ++lev) {
    int nb = 4 - lev;
    for (int idx = tid; idx < nb * 256; idx += 512) {
      int J = idx >> 8, I = J + lev;
      int i = (idx >> 4) & 15, j = idx & 15;
      float s = 0.f;
      for (int P = J; P < I; ++P)
#pragma unroll 4
        for (int p = 0; p < 16; ++p)
          s += ML[(16 * I + i) * MP + 16 * P + p] * NT[(16 * J + j) * MP + 16 * P + p];
      GB[J * 256 + i * 16 + j] = s;
    }
    __syncthreads();
    for (int idx = tid; idx < nb * 256; idx += 512) {
      int J = idx >> 8, I = J + lev;
      int i = (idx >> 4) & 15, j = idx & 15;
      float s = 0.f;
#pragma unroll 4
      for (int p = 0; p < 16; ++p)
        s += NT[(16 * I + p) * MP + 16 * I + i] * GB[J * 256 + p * 16 + j];
      NT[(16 * J + j) * MP + 16 * I + i] = -s;
    }
    __syncthreads();
  }

  // (f) RHS_z = b * k * e^cg ; Z = N * RHS_z  (tiled store)
  {
    int tW = tid >> 3, g = tid & 7;
    float b = bL[tW];
#pragma unroll
    for (int i = 0; i < 4; ++i) {
      int d = g * 16 + 4 * i;
      float4 kv = *(const float4*)(kL + tW * PCH + d);
      float4 cg4 = *(const float4*)(cgL + tW * PCH + d);
      float4 r;
      r.x = b * kv.x * __expf(cg4.x); r.y = b * kv.y * __expf(cg4.y);
      r.z = b * kv.z * __expf(cg4.z); r.w = b * kv.w * __expf(cg4.w);
      *(float4*)(qL + tW * PCH + d) = r;
    }
  }
  __syncthreads();
  {
    int t4 = tid >> 5, c4 = tid & 31;
    float acc[4][4];
#pragma unroll
    for (int i = 0; i < 4; ++i)
#pragma unroll
      for (int j = 0; j < 4; ++j) acc[i][j] = 0.f;
    for (int s = 0; s < 64; ++s) {
      float nv[4], rv[4];
      *(float4*)nv = *(const float4*)(NT + s * MP + t4 * 4);
      *(float4*)rv = *(const float4*)(qL + s * PCH + c4 * 4);
#pragma unroll
      for (int i = 0; i < 4; ++i)
#pragma unroll
        for (int j = 0; j < 4; ++j) acc[i][j] += nv[i] * rv[j];
    }
    size_t zb = (size_t)bid * 8192 + (size_t)(c4 >> 2) * 1024 + (c4 & 3) * 4;
#pragma unroll
    for (int i = 0; i < 4; ++i) {
      float4 o; o.x = acc[i][0]; o.y = acc[i][1]; o.z = acc[i][2]; o.w = acc[i][3];
      *(float4*)(z_g + zb + (size_t)(t4 * 4 + i) * 16) = o;
    }
  }
  __syncthreads();

  // (g) RHS_v = b * silu(conv(v)) ; U0 = N * RHS_v (natural store)
  for (int it = 0; it < 16; ++it) {
    int cell = tid + (it << 9);
    int d = cell & 127, t = cell >> 7;
    int ch = 2 * CH1 + h * HD + d;
    float4 w4 = ((const float4*)cw)[ch];
    int rbase = t0 + t - 3;
    float acc;
    if (rbase >= 0) {
      const float* mp = mixed + (size_t)rbase * CH3 + ch;
      acc = mp[0] * w4.x + mp[CH3] * w4.y + mp[2 * CH3] * w4.z + mp[3 * CH3] * w4.w;
    } else {
      acc = 0.f;
      if (rbase + 0 >= 0) acc += mixed[(size_t)(rbase + 0) * CH3 + ch] * w4.x;
      if (rbase + 1 >= 0) acc += mixed[(size_t)(rbase + 1) * CH3 + ch] * w4.y;
      if (rbase + 2 >= 0) acc += mixed[(size_t)(rbase + 2) * CH3 + ch] * w4.z;
      acc += mixed[(size_t)(rbase + 3) * CH3 + ch] * w4.w;
    }
    acc = acc / (1.f + __expf(-acc));
    qL[t * PCH + d] = bL[t] * acc;
  }
  __syncthreads();
  {
    int t4 = tid >> 5, c4 = tid & 31;
    float acc[4][4];
#pragma unroll
    for (int i = 0; i < 4; ++i)
#pragma unroll
      for (int j = 0; j < 4; ++j) acc[i][j] = 0.f;
    for (int s = 0; s < 64; ++s) {
      float nv[4], rv[4];
      *(float4*)nv = *(const float4*)(NT + s * MP + t4 * 4);
      *(float4*)rv = *(const float4*)(qL + s * PCH + c4 * 4);
#pragma unroll
      for (int i = 0; i < 4; ++i)
#pragma unroll
        for (int j = 0; j < 4; ++j) acc[i][j] += nv[i] * rv[j];
    }
#pragma unroll
    for (int i = 0; i < 4; ++i) {
      size_t ob = ((size_t)(t0 + t4 * 4 + i) * NH + h) * HD + c4 * 4;
      float4 o; o.x = acc[i][0]; o.y = acc[i][1]; o.z = acc[i][2]; o.w = acc[i][3];
      *(float4*)(u0_g + ob) = o;
    }
  }
}

// ---------------------------------------------------------------------------
// Kernel B v4: TLP restructure. Grid 512 = 16 h x 32 vg (4 v-cols per block);
// 2 blocks/CU (16 waves) so one block's barrier/latency stalls are covered by
// the other block's compute. Same math as v2 (the 931us best), half-width:
//   P1 (all): partial T=Z*S, O1=Q~*S over wave's 16-d slice (4 cols)
//   P2 (split): waves 0-3 reduce T -> U -> Un/Ut; waves 4-7 reduce O -> Osave
//   P3 (all): partial W*U over wave's 8-s slice
//   P4 (waves 4-7): out = Osave + reduce(W-partials)   } concurrent
//   P5 (waves 0-3): S = e*S + Kbar^T * U               } phases
// Pitch fixes from R2 kept (68-float pitches). No keep-alives, no reg
// double-buffering (R2 post-mortem: compiler re-loads rather than hold regs).
// ---------------------------------------------------------------------------
#define PT 68
#define PG 272   // 4 cols * 68

__global__ __launch_bounds__(512, 4)
void kda_scan3(const float* __restrict__ qt_g, const float* __restrict__ kbt_g,
               const float* __restrict__ u0_g, const float* __restrict__ z_g,
               const float* __restrict__ w_g, const float* __restrict__ ecg_g,
               float* __restrict__ out, float* __restrict__ slabs) {
  __shared__ float Tp[2176], Op[2176];   // [8g][4j][68]
  __shared__ float Sl[512];              // S slab [128 k][4 j]
  __shared__ float Un[256];              // U natural [64 t][4 j]
  __shared__ float Ut[272];              // U transposed [4 j][68]
  (void)slabs;
  const int tid = threadIdx.x;
  const int bid = blockIdx.x;
  const int h = bid & 15, vg = bid >> 4;      // vg in [0,32): 4 v-cols each
  const int gA = tid >> 6, tA = tid & 63;
  const int tB = (tid >> 2) & 63, jB = tid & 3;
  const int kC = tid & 127, j2 = (tid >> 7) & 1;  // P5 threads: tid < 256

  for (int i = tid; i < 512; i += 512) Sl[i] = 0.f;
  __syncthreads();

  for (int c = 0; c < NC; ++c) {
    const int ch = c * 16 + h;
    // ---- loads for chunk c, issued up front (drain at first barrier) ----
    float z[16], q[16];
    {
      const float* zb = z_g + (size_t)ch * 8192 + gA * 1024 + tA * 16;
      const float* qb = qt_g + (size_t)ch * 8192 + gA * 1024 + tA * 16;
#pragma unroll
      for (int i = 0; i < 4; ++i) {
        *(float4*)(z + 4 * i) = *(const float4*)(zb + 4 * i);
        *(float4*)(q + 4 * i) = *(const float4*)(qb + 4 * i);
      }
    }
    float w8[8];
    {
      const float* wb = w_g + (size_t)ch * 4096 + gA * 512 + tA * 8;
      *(float4*)w8 = *(const float4*)(wb);
      *(float4*)(w8 + 4) = *(const float4*)(wb + 4);
    }
    const float u0v = u0_g[((size_t)(c * 64 + tB) * NH + h) * HD + vg * 4 + jB];
    float kv[64], eC = 0.f;
    if (tid < 256) {
      const float* kb = kbt_g + (size_t)ch * 8192 + (size_t)kC * 64;
#pragma unroll
      for (int t4 = 0; t4 < 16; ++t4)
        *(float4*)(kv + 4 * t4) = *(const float4*)(kb + 4 * t4);
      eC = ecg_g[(size_t)ch * 128 + kC];
    }

    // ---- P1: partial T = Z*S, O1 = Q~*S over this wave's 16-d slice ----
    {
      float Ta[4], Oa[4];
#pragma unroll
      for (int j = 0; j < 4; ++j) { Ta[j] = 0.f; Oa[j] = 0.f; }
#pragma unroll
      for (int dd = 0; dd < 16; ++dd) {
        float s4[4];
        *(float4*)s4 = *(const float4*)(Sl + (gA * 16 + dd) * 4);
        float zz = z[dd], qq = q[dd];
#pragma unroll
        for (int j = 0; j < 4; ++j) { Ta[j] += zz * s4[j]; Oa[j] += qq * s4[j]; }
      }
#pragma unroll
      for (int j = 0; j < 4; ++j) {
        Tp[gA * PG + j * PT + tA] = Ta[j];
        Op[gA * PG + j * PT + tA] = Oa[j];
      }
    }
    __syncthreads();

    // ---- P2 (wave-split): waves 0-3: T-reduce -> U; waves 4-7: O-reduce ----
    float Osave = 0.f;
    if (tid < 256) {
      float Ts = 0.f;
#pragma unroll
      for (int g = 0; g < 8; ++g) Ts += Tp[g * PG + jB * PT + tB];
      float U = u0v - Ts;
      Un[tB * 4 + jB] = U;
      Ut[jB * PT + tB] = U;
    } else {
      float Os = 0.f;
#pragma unroll
      for (int g = 0; g < 8; ++g) Os += Op[g * PG + jB * PT + tB];
      Osave = Os;
    }
    __syncthreads();

    // ---- P3: partial W*U over this wave's 8-s slice (reuse Tp) ----
    {
      float Wa[4];
#pragma unroll
      for (int j = 0; j < 4; ++j) Wa[j] = 0.f;
#pragma unroll
      for (int sp = 0; sp < 8; ++sp) {
        float u4[4];
        *(float4*)u4 = *(const float4*)(Un + (gA * 8 + sp) * 4);
        float wv = w8[sp];
#pragma unroll
        for (int j = 0; j < 4; ++j) Wa[j] += wv * u4[j];
      }
#pragma unroll
      for (int j = 0; j < 4; ++j) Tp[gA * PG + j * PT + tA] = Wa[j];
    }
    __syncthreads();

    // ---- P4 (waves 4-7): out write  ||  P5 (waves 0-3): S update ----
    if (tid >= 256) {
      float O2 = 0.f;
#pragma unroll
      for (int g = 0; g < 8; ++g) O2 += Tp[g * PG + jB * PT + tB];
      out[((size_t)(c * 64 + tB) * NH + h) * HD + vg * 4 + jB] = Osave + O2;
    } else {
      float a0 = 0.f, a1 = 0.f;
      const float* u0r = Ut + (2 * j2) * PT;
      const float* u1r = Ut + (2 * j2 + 1) * PT;
#pragma unroll
      for (int t4 = 0; t4 < 16; ++t4) {
        float4 ua = *(const float4*)(u0r + 4 * t4);
        float4 ub = *(const float4*)(u1r + 4 * t4);
        a0 += kv[4 * t4 + 0] * ua.x + kv[4 * t4 + 1] * ua.y +
              kv[4 * t4 + 2] * ua.z + kv[4 * t4 + 3] * ua.w;
        a1 += kv[4 * t4 + 0] * ub.x + kv[4 * t4 + 1] * ub.y +
              kv[4 * t4 + 2] * ub.z + kv[4 * t4 + 3] * ub.w;
      }
      float* sp2 = Sl + kC * 4 + 2 * j2;
      float s0 = sp2[0], s1 = sp2[1];
      sp2[0] = eC * s0 + a0;
      sp2[1] = eC * s1 + a1;
    }
    __syncthreads();
  }
}

// ---------------------------------------------------------------------------
extern "C" void kernel_launch(void* const* d_in, const int* in_sizes, int n_in,
                              void* d_out, int out_size, void* d_ws, size_t ws_size,
                              hipStream_t stream) {
  const float* mixed = (const float*)d_in[0];
  const float* fg    = (const float*)d_in[1];
  const float* beta  = (const float*)d_in[2];
  const float* cw    = (const float*)d_in[3];
  const float* dtb   = (const float*)d_in[4];
  const float* alog  = (const float*)d_in[5];
  float* ws = (float*)d_ws;
  float* qt_g  = ws + QT_OFF;
  float* kbt_g = ws + KBT_OFF;
  float* u0_g  = ws + U0_OFF;
  float* z_g   = ws + Z_OFF;
  float* w_g   = ws + W_OFF;
  float* ecg_g = ws + ECG_OFF;
  float* slabs = ws + SLAB_OFF;

  hipLaunchKernelGGL(kda_chunk, dim3(NC * NH), dim3(512), 0, stream,
                     mixed, fg, beta, cw, dtb, alog,
                     qt_g, kbt_g, u0_g, z_g, w_g, ecg_g);
  hipLaunchKernelGGL(kda_scan3, dim3(512), dim3(512), 0, stream,
                     qt_g, kbt_g, u0_g, z_g, w_g, ecg_g, (float*)d_out, slabs);
  (void)in_sizes; (void)n_in; (void)out_size; (void)ws_size;
}

// Round 4
// 1847.414 us; speedup vs baseline: 1.2257x; 1.2257x over previous
//
#include <hip/hip_runtime.h>
#include <math.h>

#define NH 16
#define HD 128
#define CH1 2048
#define CH3 6144
#define CK 64
#define NC 128
#define PCH 132   // LDS pitch for 64x128 tensors (bank-friendly, 16B-aligned rows)
#define MP 68     // LDS pitch for 64x64 M / N^T

// workspace layout (float offsets)
#define QT_OFF  0u            // tiled q~   [2048 ch][8g][64t][16d]
#define KBT_OFF 16777216u     // kbar^T     [2048 ch][128k][64t]
#define U0_OFF  33554432u     // U0 natural [8192 t][16 h][128 d]
#define Z_OFF   50331648u     // tiled Z    [2048 ch][8g][64t][16d]
#define W_OFF   67108864u     // tiled W    [2048 ch][8g][64t][8s]
#define ECG_OFF 75497472u     // e^{cg63}   [2048 ch][128 k]
#define SLAB_OFF 75759616u    // (unused by scan3; kept for layout stability)

// ---------------------------------------------------------------------------
// Kernel A: per-(chunk, head) fully parallel. conv+silu+l2norm+gates, then
// A/W pair-matrices, (I+B A)^-1, Z, U0.
// R4 change: phase (d) d-split over 272 threads (was 136; 73% of lanes idle).
// ---------------------------------------------------------------------------
__global__ __launch_bounds__(512, 2)
void kda_chunk(const float* __restrict__ mixed, const float* __restrict__ fg,
               const float* __restrict__ beta, const float* __restrict__ cw,
               const float* __restrict__ dtb, const float* __restrict__ alog,
               float* __restrict__ qt_g, float* __restrict__ kbt_g,
               float* __restrict__ u0_g, float* __restrict__ z_g,
               float* __restrict__ w_g, float* __restrict__ ecg_g) {
  __shared__ float lds[35520];
  float* kL  = lds;            // [64][132]
  float* qL  = lds + 8448;     // [64][132], later RHS
  float* cgL = lds + 16896;    // [64][132]
  float* ML  = lds + 25344;    // [64][68]
  float* NT  = lds + 29696;    // [64][68]  (N transposed); also (d) scratch
  float* GB  = lds + 34048;    // [768]
  float* bL  = lds + 34816;    // [64]
  float* nrm = lds + 34880;    // [640]

  const int tid = threadIdx.x;
  const int bid = blockIdx.x;
  const int c = bid >> 4, h = bid & 15;
  const int t0 = c * CK;
  const float ea = __expf(alog[h]);

  // W zero-fill (store-before-barrier ordering makes later overwrites safe)
  {
    size_t wb = (size_t)bid * 4096;
#pragma unroll
    for (int i = 0; i < 8; ++i) w_g[wb + tid + 512 * i] = 0.f;
  }

  // (a) g = -exp(alog)*softplus(fg+dtb) -> cgL
  for (int it = 0; it < 16; ++it) {
    int cell = tid + (it << 9);
    int d = cell & 127, t = cell >> 7;
    float x = fg[(size_t)(t0 + t) * CH1 + h * HD + d] + dtb[h * HD + d];
    float sp = (x > 20.f) ? x : log1pf(__expf(x));
    cgL[t * PCH + d] = -ea * sp;
  }
  if (tid < 64) bL[tid] = 1.f / (1.f + __expf(-beta[(size_t)(t0 + tid) * NH + h]));
  __syncthreads();

  // inclusive prefix over t (per dim) + ecg writeout
  if (tid < 128) {
    float a = 0.f;
    for (int t = 0; t < 64; ++t) { a += cgL[t * PCH + tid]; cgL[t * PCH + tid] = a; }
    ecg_g[(size_t)bid * 128 + tid] = __expf(a);
  }

  // (b) conv+silu for q (sec0) and k (sec1)
  for (int it = 0; it < 32; ++it) {
    int cell = tid + (it << 9);
    int d = cell & 127, sec = (cell >> 7) & 1, t = cell >> 8;
    int ch = sec * CH1 + h * HD + d;
    float4 w4 = ((const float4*)cw)[ch];
    int rbase = t0 + t - 3;
    float acc;
    if (rbase >= 0) {
      const float* mp = mixed + (size_t)rbase * CH3 + ch;
      acc = mp[0] * w4.x + mp[CH3] * w4.y + mp[2 * CH3] * w4.z + mp[3 * CH3] * w4.w;
    } else {
      acc = 0.f;
      if (rbase + 0 >= 0) acc += mixed[(size_t)(rbase + 0) * CH3 + ch] * w4.x;
      if (rbase + 1 >= 0) acc += mixed[(size_t)(rbase + 1) * CH3 + ch] * w4.y;
      if (rbase + 2 >= 0) acc += mixed[(size_t)(rbase + 2) * CH3 + ch] * w4.z;
      acc += mixed[(size_t)(rbase + 3) * CH3 + ch] * w4.w;
    }
    acc = acc / (1.f + __expf(-acc));
    float* dst = (sec == 0) ? qL : kL;
    dst[t * PCH + d] = acc;
  }
  __syncthreads();

  // l2norm partials
  {
    int sec = tid >> 8, t = (tid >> 2) & 63, r = tid & 3;
    const float* src = (sec == 0) ? qL : kL;
    float s = 0.f;
#pragma unroll
    for (int i = 0; i < 8; ++i) {
      float4 v = *(const float4*)(src + t * PCH + r * 32 + i * 4);
      s += v.x * v.x + v.y * v.y + v.z * v.z + v.w * v.w;
    }
    nrm[tid] = s;
  }
  __syncthreads();
  if (tid < 128) {
    int sec = tid >> 6, t = tid & 63;
    float s = nrm[sec * 256 + t * 4] + nrm[sec * 256 + t * 4 + 1] +
              nrm[sec * 256 + t * 4 + 2] + nrm[sec * 256 + t * 4 + 3];
    float inv = rsqrtf(s + 1e-6f);
    if (sec == 0) inv *= 0.08838834764831845f;  // q scale D^-0.5
    nrm[512 + tid] = inv;
  }
  __syncthreads();
  for (int it = 0; it < 8; ++it) {
    int f4 = tid + (it << 9);
    int sec = f4 >> 11, t = (f4 >> 5) & 63, d4 = f4 & 31;
    float* dst = (sec == 0) ? qL : kL;
    float inv = nrm[512 + sec * 64 + t];
    float4 v = *(float4*)(dst + t * PCH + d4 * 4);
    v.x *= inv; v.y *= inv; v.z *= inv; v.w *= inv;
    *(float4*)(dst + t * PCH + d4 * 4) = v;
  }
  __syncthreads();

  // (c) writeouts: q~ (tiled), kbar^T
  {
    int tW = tid >> 3, g = tid & 7;
    size_t qb = (size_t)bid * 8192 + g * 1024 + tW * 16;
    size_t kb = (size_t)bid * 8192;
#pragma unroll
    for (int i = 0; i < 4; ++i) {
      int d = g * 16 + 4 * i;
      float4 qv = *(const float4*)(qL + tW * PCH + d);
      float4 cg4 = *(const float4*)(cgL + tW * PCH + d);
      float4 o;
      o.x = qv.x * __expf(cg4.x); o.y = qv.y * __expf(cg4.y);
      o.z = qv.z * __expf(cg4.z); o.w = qv.w * __expf(cg4.w);
      *(float4*)(qt_g + qb + 4 * i) = o;
      float4 kv = *(const float4*)(kL + tW * PCH + d);
      float4 c63 = *(const float4*)(cgL + 63 * PCH + d);
      kbt_g[kb + (size_t)(d + 0) * 64 + tW] = kv.x * __expf(c63.x - cg4.x);
      kbt_g[kb + (size_t)(d + 1) * 64 + tW] = kv.y * __expf(c63.y - cg4.y);
      kbt_g[kb + (size_t)(d + 2) * 64 + tW] = kv.z * __expf(c63.z - cg4.z);
      kbt_g[kb + (size_t)(d + 3) * 64 + tW] = kv.w * __expf(c63.w - cg4.w);
    }
  }

  // (d) pair-work: A (strict lower, scaled by b -> M) and W (incl lower).
  // 4x4 (t,s) tiles, lower-tri set (136), d-split x2 -> 272 active threads.
  int taD = 0, saD = 0;
  float accA[16], accW[16];
  if (tid < 272) {
    int L = tid >> 1, dh = tid & 1;
    int tt = (int)((sqrtf(8.f * L + 1.f) - 1.f) * 0.5f);
    while ((tt + 1) * (tt + 2) / 2 <= L) ++tt;
    while (tt * (tt + 1) / 2 > L) --tt;
    int ss = L - tt * (tt + 1) / 2;
    taD = tt * 4; saD = ss * 4;
#pragma unroll
    for (int i = 0; i < 16; ++i) { accA[i] = 0.f; accW[i] = 0.f; }
    int d0 = dh << 6;
    for (int d = d0; d < d0 + 64; d += 4) {
      float kt[4][4], qt4[4][4], ct[4][4], ks4[4][4], cs4[4][4];
#pragma unroll
      for (int i = 0; i < 4; ++i) {
        *(float4*)kt[i]  = *(const float4*)(kL + (taD + i) * PCH + d);
        *(float4*)qt4[i] = *(const float4*)(qL + (taD + i) * PCH + d);
        *(float4*)ct[i]  = *(const float4*)(cgL + (taD + i) * PCH + d);
        *(float4*)ks4[i] = *(const float4*)(kL + (saD + i) * PCH + d);
        *(float4*)cs4[i] = *(const float4*)(cgL + (saD + i) * PCH + d);
      }
#pragma unroll
      for (int i = 0; i < 4; ++i)
#pragma unroll
        for (int j = 0; j < 4; ++j)
#pragma unroll
          for (int dd = 0; dd < 4; ++dd) {
            float diff = ct[i][dd] - cs4[j][dd];
            float e = __expf(fminf(diff, 0.f));
            float m = e * ks4[j][dd];
            accA[i * 4 + j] += kt[i][dd] * m;
            accW[i * 4 + j] += qt4[i][dd] * m;
          }
    }
    if (dh) {  // stash upper-half partials in NT scratch (zeroed later anyway)
#pragma unroll
      for (int i = 0; i < 16; ++i) {
        NT[L * 32 + i] = accA[i];
        NT[L * 32 + 16 + i] = accW[i];
      }
    }
  }
  __syncthreads();
  if (tid < 272 && !(tid & 1)) {
    int L = tid >> 1;
#pragma unroll
    for (int i = 0; i < 16; ++i) {
      accA[i] += NT[L * 32 + i];
      accW[i] += NT[L * 32 + 16 + i];
    }
    size_t wb = (size_t)bid * 4096;
#pragma unroll
    for (int i = 0; i < 4; ++i)
#pragma unroll
      for (int j = 0; j < 4; ++j) {
        int t = taD + i, s = saD + j;
        if (s < t) ML[t * MP + s] = bL[t] * accA[i * 4 + j];
        float wv = (s <= t) ? accW[i * 4 + j] : 0.f;
        w_g[wb + (size_t)(s >> 3) * 512 + t * 8 + (s & 7)] = wv;
      }
  }
  __syncthreads();

  // (e) N = (I + B A)^-1, stored transposed in NT
  for (int i = tid; i < 4352; i += 512) NT[i] = 0.f;
  __syncthreads();
  if (tid < 64) {
    int b4 = tid >> 4, j = tid & 15, bo = b4 * 16;
    NT[(bo + j) * MP + bo + j] = 1.f;
    for (int t = j + 1; t < 16; ++t) {
      float s = 0.f;
      for (int sx = j; sx < t; ++sx)
        s += ML[(bo + t) * MP + bo + sx] * NT[(bo + j) * MP + bo + sx];
      NT[(bo + j) * MP + bo + t] = -s;
    }
  }
  __syncthreads();
  for (int lev = 1; lev <= 3; ++lev) {
    int nb = 4 - lev;
    for (int idx = tid; idx < nb * 256; idx += 512) {
      int J = idx >> 8, I = J + lev;
      int i = (idx >> 4) & 15, j = idx & 15;
      float s = 0.f;
      for (int P = J; P < I; ++P)
#pragma unroll 4
        for (int p = 0; p < 16; ++p)
          s += ML[(16 * I + i) * MP + 16 * P + p] * NT[(16 * J + j) * MP + 16 * P + p];
      GB[J * 256 + i * 16 + j] = s;
    }
    __syncthreads();
    for (int idx = tid; idx < nb * 256; idx += 512) {
      int J = idx >> 8, I = J + lev;
      int i = (idx >> 4) & 15, j = idx & 15;
      float s = 0.f;
#pragma unroll 4
      for (int p = 0; p < 16; ++p)
        s += NT[(16 * I + p) * MP + 16 * I + i] * GB[J * 256 + p * 16 + j];
      NT[(16 * J + j) * MP + 16 * I + i] = -s;
    }
    __syncthreads();
  }

  // (f) RHS_z = b * k * e^cg ; Z = N * RHS_z  (tiled store)
  {
    int tW = tid >> 3, g = tid & 7;
    float b = bL[tW];
#pragma unroll
    for (int i = 0; i < 4; ++i) {
      int d = g * 16 + 4 * i;
      float4 kv = *(const float4*)(kL + tW * PCH + d);
      float4 cg4 = *(const float4*)(cgL + tW * PCH + d);
      float4 r;
      r.x = b * kv.x * __expf(cg4.x); r.y = b * kv.y * __expf(cg4.y);
      r.z = b * kv.z * __expf(cg4.z); r.w = b * kv.w * __expf(cg4.w);
      *(float4*)(qL + tW * PCH + d) = r;
    }
  }
  __syncthreads();
  {
    int t4 = tid >> 5, c4 = tid & 31;
    float acc[4][4];
#pragma unroll
    for (int i = 0; i < 4; ++i)
#pragma unroll
      for (int j = 0; j < 4; ++j) acc[i][j] = 0.f;
    for (int s = 0; s < 64; ++s) {
      float nv[4], rv[4];
      *(float4*)nv = *(const float4*)(NT + s * MP + t4 * 4);
      *(float4*)rv = *(const float4*)(qL + s * PCH + c4 * 4);
#pragma unroll
      for (int i = 0; i < 4; ++i)
#pragma unroll
        for (int j = 0; j < 4; ++j) acc[i][j] += nv[i] * rv[j];
    }
    size_t zb = (size_t)bid * 8192 + (size_t)(c4 >> 2) * 1024 + (c4 & 3) * 4;
#pragma unroll
    for (int i = 0; i < 4; ++i) {
      float4 o; o.x = acc[i][0]; o.y = acc[i][1]; o.z = acc[i][2]; o.w = acc[i][3];
      *(float4*)(z_g + zb + (size_t)(t4 * 4 + i) * 16) = o;
    }
  }
  __syncthreads();

  // (g) RHS_v = b * silu(conv(v)) ; U0 = N * RHS_v (natural store)
  for (int it = 0; it < 16; ++it) {
    int cell = tid + (it << 9);
    int d = cell & 127, t = cell >> 7;
    int ch = 2 * CH1 + h * HD + d;
    float4 w4 = ((const float4*)cw)[ch];
    int rbase = t0 + t - 3;
    float acc;
    if (rbase >= 0) {
      const float* mp = mixed + (size_t)rbase * CH3 + ch;
      acc = mp[0] * w4.x + mp[CH3] * w4.y + mp[2 * CH3] * w4.z + mp[3 * CH3] * w4.w;
    } else {
      acc = 0.f;
      if (rbase + 0 >= 0) acc += mixed[(size_t)(rbase + 0) * CH3 + ch] * w4.x;
      if (rbase + 1 >= 0) acc += mixed[(size_t)(rbase + 1) * CH3 + ch] * w4.y;
      if (rbase + 2 >= 0) acc += mixed[(size_t)(rbase + 2) * CH3 + ch] * w4.z;
      acc += mixed[(size_t)(rbase + 3) * CH3 + ch] * w4.w;
    }
    acc = acc / (1.f + __expf(-acc));
    qL[t * PCH + d] = bL[t] * acc;
  }
  __syncthreads();
  {
    int t4 = tid >> 5, c4 = tid & 31;
    float acc[4][4];
#pragma unroll
    for (int i = 0; i < 4; ++i)
#pragma unroll
      for (int j = 0; j < 4; ++j) acc[i][j] = 0.f;
    for (int s = 0; s < 64; ++s) {
      float nv[4], rv[4];
      *(float4*)nv = *(const float4*)(NT + s * MP + t4 * 4);
      *(float4*)rv = *(const float4*)(qL + s * PCH + c4 * 4);
#pragma unroll
      for (int i = 0; i < 4; ++i)
#pragma unroll
        for (int j = 0; j < 4; ++j) acc[i][j] += nv[i] * rv[j];
    }
#pragma unroll
    for (int i = 0; i < 4; ++i) {
      size_t ob = ((size_t)(t0 + t4 * 4 + i) * NH + h) * HD + c4 * 4;
      float4 o; o.x = acc[i][0]; o.y = acc[i][1]; o.z = acc[i][2]; o.w = acc[i][3];
      *(float4*)(u0_g + ob) = o;
    }
  }
}

// ---------------------------------------------------------------------------
// Kernel B v5: grid 256 (16 h x 16 vg, 8 v-cols) -- R3 showed v-splitting
// further duplicates shared-operand traffic (z,q,w,kbt are kxt-shaped), so
// keep R1's width and cut the serial phase chain instead:
//   3 barriers/chunk (was 4) with concurrent wave-split phases:
//   phase1: [w4-7: PREV chunk P4 out-reduce/write] || [all: P1 T/O partials]
//   phase2: [w0-3: T-reduce -> U -> Un/Ut]         || [w4-7: O-reduce -> regs]
//   phase3: [w0-3: P5 S-update]                    || [w4-7: P3 W*U -> Wp]
// P4 is deferred one chunk (dedicated Wp buffer breaks the Tp reuse hazard),
// taking the out-write off the serial S-chain. Sl pitch 12 (bank spread).
// ---------------------------------------------------------------------------
#define PT 68
#define PG 544   // 8 j * 68

__global__ __launch_bounds__(512, 2)
void kda_scan3(const float* __restrict__ qt_g, const float* __restrict__ kbt_g,
               const float* __restrict__ u0_g, const float* __restrict__ z_g,
               const float* __restrict__ w_g, const float* __restrict__ ecg_g,
               float* __restrict__ out, float* __restrict__ slabs) {
  __shared__ float Tp[4352], Op[4352];   // [8g][8j][68]
  __shared__ float Wp[2176];             // [4g][8j][68]
  __shared__ float Sl[1536];             // [128 k][12 pitch] (8 j used)
  __shared__ float Un[512];              // [64 t][8 j]
  __shared__ float Ut[544];              // [8 j][68]
  (void)slabs;
  const int tid = threadIdx.x;
  const int bid = blockIdx.x;
  const int h = bid & 15, vg = bid >> 4;
  const int gA = tid >> 6, tA = tid & 63;
  const int tH = (tid & 255) >> 2;        // 0..63 (both half-sets)
  const int jH = (tid & 3) << 1;          // 0,2,4,6 (pairs jH, jH+1)
  const int kC = tid & 127;               // lo half: S row
  const int jq = ((tid >> 7) & 1) << 2;   // lo half: j-quad 0 or 4
  const int gB = (tid >> 6) & 3;          // hi half: s-group 0..3

  for (int i = tid; i < 1536; i += 512) Sl[i] = 0.f;
  __syncthreads();

  float OsA = 0.f, OsB = 0.f;            // hi half: deferred O1 sums

  for (int c = 0; c < NC; ++c) {
    const int ch = c * 16 + h;
    // ---- loads for chunk c, issued up front ----
    float z[16], q[16];
    {
      const float* zb = z_g + (size_t)ch * 8192 + gA * 1024 + tA * 16;
      const float* qb = qt_g + (size_t)ch * 8192 + gA * 1024 + tA * 16;
#pragma unroll
      for (int i = 0; i < 4; ++i) {
        *(float4*)(z + 4 * i) = *(const float4*)(zb + 4 * i);
        *(float4*)(q + 4 * i) = *(const float4*)(qb + 4 * i);
      }
    }
    float w16[16];   // hi: W[t=tA][s = gB*16 .. +16]
    float u0a = 0.f, u0b = 0.f;
    float kv[64], eC = 0.f;
    if (tid < 256) {
      const float* kb = kbt_g + (size_t)ch * 8192 + (size_t)kC * 64;
#pragma unroll
      for (int t4 = 0; t4 < 16; ++t4)
        *(float4*)(kv + 4 * t4) = *(const float4*)(kb + 4 * t4);
      eC = ecg_g[(size_t)ch * 128 + kC];
      const float* ub = u0_g + ((size_t)(c * 64 + tH) * NH + h) * HD + vg * 8 + jH;
      u0a = ub[0]; u0b = ub[1];
    } else {
      const float* wb = w_g + (size_t)ch * 4096 + (size_t)(gB * 2) * 512 + tA * 8;
      *(float4*)w16       = *(const float4*)(wb);
      *(float4*)(w16 + 4) = *(const float4*)(wb + 4);
      *(float4*)(w16 + 8)  = *(const float4*)(wb + 512);
      *(float4*)(w16 + 12) = *(const float4*)(wb + 516);
    }

    // ---- phase1: [hi: prev-chunk P4] || [all: P1 partials] ----
    if (tid >= 256 && c > 0) {
      float O2a = 0.f, O2b = 0.f;
#pragma unroll
      for (int g = 0; g < 4; ++g) {
        O2a += Wp[g * PG + jH * PT + tH];
        O2b += Wp[g * PG + (jH + 1) * PT + tH];
      }
      float* ob = out + ((size_t)((c - 1) * 64 + tH) * NH + h) * HD + vg * 8 + jH;
      ob[0] = OsA + O2a; ob[1] = OsB + O2b;
    }
    {
      float Ta[8], Oa[8];
#pragma unroll
      for (int j = 0; j < 8; ++j) { Ta[j] = 0.f; Oa[j] = 0.f; }
#pragma unroll
      for (int dd = 0; dd < 16; ++dd) {
        float s8[8];
        const float* sr = Sl + (gA * 16 + dd) * 12;
        *(float4*)s8 = *(const float4*)(sr);
        *(float4*)(s8 + 4) = *(const float4*)(sr + 4);
        float zz = z[dd], qq = q[dd];
#pragma unroll
        for (int j = 0; j < 8; ++j) { Ta[j] += zz * s8[j]; Oa[j] += qq * s8[j]; }
      }
#pragma unroll
      for (int j = 0; j < 8; ++j) {
        Tp[gA * PG + j * PT + tA] = Ta[j];
        Op[gA * PG + j * PT + tA] = Oa[j];
      }
    }
    __syncthreads();

    // ---- phase2: [lo: T-reduce -> U] || [hi: O-reduce -> regs] ----
    if (tid < 256) {
      float Tsa = 0.f, Tsb = 0.f;
#pragma unroll
      for (int g = 0; g < 8; ++g) {
        Tsa += Tp[g * PG + jH * PT + tH];
        Tsb += Tp[g * PG + (jH + 1) * PT + tH];
      }
      float Ua = u0a - Tsa, Ub = u0b - Tsb;
      Un[tH * 8 + jH] = Ua; Un[tH * 8 + jH + 1] = Ub;
      Ut[jH * PT + tH] = Ua; Ut[(jH + 1) * PT + tH] = Ub;
    } else {
      float Os1 = 0.f, Os2 = 0.f;
#pragma unroll
      for (int g = 0; g < 8; ++g) {
        Os1 += Op[g * PG + jH * PT + tH];
        Os2 += Op[g * PG + (jH + 1) * PT + tH];
      }
      OsA = Os1; OsB = Os2;
    }
    __syncthreads();

    // ---- phase3: [lo: P5 S-update] || [hi: P3 W*U partials -> Wp] ----
    if (tid < 256) {
      float a0 = 0.f, a1 = 0.f, a2 = 0.f, a3 = 0.f;
      const float* u0r = Ut + (jq + 0) * PT;
      const float* u1r = Ut + (jq + 1) * PT;
      const float* u2r = Ut + (jq + 2) * PT;
      const float* u3r = Ut + (jq + 3) * PT;
#pragma unroll
      for (int t4 = 0; t4 < 16; ++t4) {
        float k0 = kv[4 * t4], k1 = kv[4 * t4 + 1], k2 = kv[4 * t4 + 2], k3 = kv[4 * t4 + 3];
        float4 ua = *(const float4*)(u0r + 4 * t4);
        float4 ub = *(const float4*)(u1r + 4 * t4);
        float4 uc = *(const float4*)(u2r + 4 * t4);
        float4 ud = *(const float4*)(u3r + 4 * t4);
        a0 += k0 * ua.x + k1 * ua.y + k2 * ua.z + k3 * ua.w;
        a1 += k0 * ub.x + k1 * ub.y + k2 * ub.z + k3 * ub.w;
        a2 += k0 * uc.x + k1 * uc.y + k2 * uc.z + k3 * uc.w;
        a3 += k0 * ud.x + k1 * ud.y + k2 * ud.z + k3 * ud.w;
      }
      float* sp = Sl + kC * 12 + jq;
      float4 s = *(float4*)sp;
      s.x = eC * s.x + a0; s.y = eC * s.y + a1;
      s.z = eC * s.z + a2; s.w = eC * s.w + a3;
      *(float4*)sp = s;
    } else {
      float Wa[8];
#pragma unroll
      for (int j = 0; j < 8; ++j) Wa[j] = 0.f;
#pragma unroll
      for (int sp = 0; sp < 16; ++sp) {
        const float* ur = Un + (gB * 16 + sp) * 8;
        float u8[8];
        *(float4*)u8 = *(const float4*)(ur);
        *(float4*)(u8 + 4) = *(const float4*)(ur + 4);
        float wv = w16[sp];
#pragma unroll
        for (int j = 0; j < 8; ++j) Wa[j] += wv * u8[j];
      }
#pragma unroll
      for (int j = 0; j < 8; ++j) Wp[gB * PG + j * PT + tA] = Wa[j];
    }
    __syncthreads();
  }

  // ---- epilogue: final P4 for chunk NC-1 ----
  if (tid >= 256) {
    float O2a = 0.f, O2b = 0.f;
#pragma unroll
    for (int g = 0; g < 4; ++g) {
      O2a += Wp[g * PG + jH * PT + tH];
      O2b += Wp[g * PG + (jH + 1) * PT + tH];
    }
    float* ob = out + ((size_t)((NC - 1) * 64 + tH) * NH + h) * HD + vg * 8 + jH;
    ob[0] = OsA + O2a; ob[1] = OsB + O2b;
  }
}

// ---------------------------------------------------------------------------
extern "C" void kernel_launch(void* const* d_in, const int* in_sizes, int n_in,
                              void* d_out, int out_size, void* d_ws, size_t ws_size,
                              hipStream_t stream) {
  const float* mixed = (const float*)d_in[0];
  const float* fg    = (const float*)d_in[1];
  const float* beta  = (const float*)d_in[2];
  const float* cw    = (const float*)d_in[3];
  const float* dtb   = (const float*)d_in[4];
  const float* alog  = (const float*)d_in[5];
  float* ws = (float*)d_ws;
  float* qt_g  = ws + QT_OFF;
  float* kbt_g = ws + KBT_OFF;
  float* u0_g  = ws + U0_OFF;
  float* z_g   = ws + Z_OFF;
  float* w_g   = ws + W_OFF;
  float* ecg_g = ws + ECG_OFF;
  float* slabs = ws + SLAB_OFF;

  hipLaunchKernelGGL(kda_chunk, dim3(NC * NH), dim3(512), 0, stream,
                     mixed, fg, beta, cw, dtb, alog,
                     qt_g, kbt_g, u0_g, z_g, w_g, ecg_g);
  hipLaunchKernelGGL(kda_scan3, dim3(256), dim3(512), 0, stream,
                     qt_g, kbt_g, u0_g, z_g, w_g, ecg_g, (float*)d_out, slabs);
  (void)in_sizes; (void)n_in; (void)out_size; (void)ws_size;
}

// Round 5
// 1621.289 us; speedup vs baseline: 1.3966x; 1.1395x over previous
//
#include <hip/hip_runtime.h>
#include <math.h>

#define NH 16
#define HD 128
#define CH1 2048
#define CH3 6144
#define CK 64
#define NC 128
#define PCH 132   // LDS pitch for 64x128 tensors (16B-aligned rows)
#define MP 68     // LDS pitch for 64x64 M / N^T

// workspace layout (float offsets)
#define QT_OFF  0u            // tiled q~   [2048 ch][8g][64t][16d]
#define KBT_OFF 16777216u     // kbar^T     [2048 ch][128k][64t]
#define U0_OFF  33554432u     // U0 natural [8192 t][16 h][128 d]
#define Z_OFF   50331648u     // tiled Z    [2048 ch][8g][64t][16d]
#define W_OFF   67108864u     // tiled W    [2048 ch][8g][64t][8s]
#define ECG_OFF 75497472u     // e^{cg63}   [2048 ch][128 k]
#define SLAB_OFF 75759616u    // (unused by scan3; kept for layout stability)

// ---------------------------------------------------------------------------
// Kernel A v2: 1024 threads (16 waves -> 4 waves/SIMD; LDS 142KB forces
// 1 block/CU, so occupancy comes from block width). Phase (d): 4-way d-split
// (544 lanes) reduced with quad-local shfl_xor; d-column rotation breaks the
// PCH=132 (==4 mod 32) bank aliasing that caused 36M conflicts.
// ---------------------------------------------------------------------------
__global__ __launch_bounds__(1024, 4)
void kda_chunk(const float* __restrict__ mixed, const float* __restrict__ fg,
               const float* __restrict__ beta, const float* __restrict__ cw,
               const float* __restrict__ dtb, const float* __restrict__ alog,
               float* __restrict__ qt_g, float* __restrict__ kbt_g,
               float* __restrict__ u0_g, float* __restrict__ z_g,
               float* __restrict__ w_g, float* __restrict__ ecg_g) {
  __shared__ float lds[36032];
  float* kL  = lds;            // [64][132]
  float* qL  = lds + 8448;     // [64][132], later RHS
  float* cgL = lds + 16896;    // [64][132]
  float* ML  = lds + 25344;    // [64][68]
  float* NT  = lds + 29696;    // [64][68]  (N transposed)
  float* GB  = lds + 34048;    // [768]
  float* bL  = lds + 34816;    // [64]
  float* nrm = lds + 34880;    // [1152]

  const int tid = threadIdx.x;
  const int bid = blockIdx.x;
  const int c = bid >> 4, h = bid & 15;
  const int t0 = c * CK;
  const float ea = __expf(alog[h]);

  // W zero-fill (4096 floats)
  {
    size_t wb = (size_t)bid * 4096;
#pragma unroll
    for (int i = 0; i < 4; ++i) w_g[wb + tid + 1024 * i] = 0.f;
  }

  // (a) g = -exp(alog)*softplus(fg+dtb) -> cgL  (8192 cells)
  for (int it = 0; it < 8; ++it) {
    int cell = tid + (it << 10);
    int d = cell & 127, t = cell >> 7;
    float x = fg[(size_t)(t0 + t) * CH1 + h * HD + d] + dtb[h * HD + d];
    float sp = (x > 20.f) ? x : log1pf(__expf(x));
    cgL[t * PCH + d] = -ea * sp;
  }
  if (tid < 64) bL[tid] = 1.f / (1.f + __expf(-beta[(size_t)(t0 + tid) * NH + h]));
  __syncthreads();

  // inclusive prefix over t (per dim) + ecg writeout (concurrent with (b))
  if (tid < 128) {
    float a = 0.f;
    for (int t = 0; t < 64; ++t) { a += cgL[t * PCH + tid]; cgL[t * PCH + tid] = a; }
    ecg_g[(size_t)bid * 128 + tid] = __expf(a);
  }

  // (b) conv+silu for q (sec0) and k (sec1)  (16384 cells)
  for (int it = 0; it < 16; ++it) {
    int cell = tid + (it << 10);
    int d = cell & 127, sec = (cell >> 7) & 1, t = cell >> 8;
    int ch = sec * CH1 + h * HD + d;
    float4 w4 = ((const float4*)cw)[ch];
    int rbase = t0 + t - 3;
    float acc;
    if (rbase >= 0) {
      const float* mp = mixed + (size_t)rbase * CH3 + ch;
      acc = mp[0] * w4.x + mp[CH3] * w4.y + mp[2 * CH3] * w4.z + mp[3 * CH3] * w4.w;
    } else {
      acc = 0.f;
      if (rbase + 0 >= 0) acc += mixed[(size_t)(rbase + 0) * CH3 + ch] * w4.x;
      if (rbase + 1 >= 0) acc += mixed[(size_t)(rbase + 1) * CH3 + ch] * w4.y;
      if (rbase + 2 >= 0) acc += mixed[(size_t)(rbase + 2) * CH3 + ch] * w4.z;
      acc += mixed[(size_t)(rbase + 3) * CH3 + ch] * w4.w;
    }
    acc = acc / (1.f + __expf(-acc));
    float* dst = (sec == 0) ? qL : kL;
    dst[t * PCH + d] = acc;
  }
  __syncthreads();

  // l2norm partials: 8 threads per (sec,t) row
  {
    int sec = tid >> 9, t = (tid >> 3) & 63, r = tid & 7;
    const float* src = (sec == 0) ? qL : kL;
    float s = 0.f;
#pragma unroll
    for (int i = 0; i < 4; ++i) {
      float4 v = *(const float4*)(src + t * PCH + r * 16 + i * 4);
      s += v.x * v.x + v.y * v.y + v.z * v.z + v.w * v.w;
    }
    nrm[tid] = s;
  }
  __syncthreads();
  if (tid < 128) {
    int sec = tid >> 6, t = tid & 63;
    float s = 0.f;
#pragma unroll
    for (int r = 0; r < 8; ++r) s += nrm[sec * 512 + t * 8 + r];
    float inv = rsqrtf(s + 1e-6f);
    if (sec == 0) inv *= 0.08838834764831845f;  // q scale D^-0.5
    nrm[1024 + tid] = inv;
  }
  __syncthreads();
  for (int it = 0; it < 4; ++it) {
    int f4 = tid + (it << 10);
    int sec = f4 >> 11, t = (f4 >> 5) & 63, d4 = f4 & 31;
    float* dst = (sec == 0) ? qL : kL;
    float inv = nrm[1024 + sec * 64 + t];
    float4 v = *(float4*)(dst + t * PCH + d4 * 4);
    v.x *= inv; v.y *= inv; v.z *= inv; v.w *= inv;
    *(float4*)(dst + t * PCH + d4 * 4) = v;
  }
  __syncthreads();

  // (c) writeouts: q~ (tiled), kbar^T.  64 t x 16 d-groups of 8.
  {
    int tW = tid >> 4, g = tid & 15;
    size_t qb = (size_t)bid * 8192 + (size_t)(g >> 1) * 1024 + tW * 16 + (g & 1) * 8;
    size_t kb = (size_t)bid * 8192;
#pragma unroll
    for (int i = 0; i < 2; ++i) {
      int d = g * 8 + 4 * i;
      float4 qv = *(const float4*)(qL + tW * PCH + d);
      float4 cg4 = *(const float4*)(cgL + tW * PCH + d);
      float4 o;
      o.x = qv.x * __expf(cg4.x); o.y = qv.y * __expf(cg4.y);
      o.z = qv.z * __expf(cg4.z); o.w = qv.w * __expf(cg4.w);
      *(float4*)(qt_g + qb + 4 * i) = o;
      float4 kv = *(const float4*)(kL + tW * PCH + d);
      float4 c63 = *(const float4*)(cgL + 63 * PCH + d);
      kbt_g[kb + (size_t)(d + 0) * 64 + tW] = kv.x * __expf(c63.x - cg4.x);
      kbt_g[kb + (size_t)(d + 1) * 64 + tW] = kv.y * __expf(c63.y - cg4.y);
      kbt_g[kb + (size_t)(d + 2) * 64 + tW] = kv.z * __expf(c63.z - cg4.z);
      kbt_g[kb + (size_t)(d + 3) * 64 + tW] = kv.w * __expf(c63.w - cg4.w);
    }
  }

  // (d) pair-work: A (strict lower, scaled by b -> M) and W (incl lower).
  // 136 lower-tri 4x4 (t,s) tiles x 4-way d-split = 544 lanes; quad shfl reduce.
  if (tid < 544) {
    int L = tid >> 2, dh = tid & 3;
    int tt = (int)((sqrtf(8.f * L + 1.f) - 1.f) * 0.5f);
    while ((tt + 1) * (tt + 2) / 2 <= L) ++tt;
    while (tt * (tt + 1) / 2 > L) --tt;
    int ss = L - tt * (tt + 1) / 2;
    int taD = tt * 4, saD = ss * 4;
    float accA[16], accW[16];
#pragma unroll
    for (int i = 0; i < 16; ++i) { accA[i] = 0.f; accW[i] = 0.f; }
    for (int s4 = 0; s4 < 8; ++s4) {
      // rotated d-column: quad lanes 8 words apart, consecutive tiles offset
      int d = (dh << 5) + (((s4 + L + (dh << 1)) & 7) << 2);
      float ks4v[4][4], cs4v[4][4];
#pragma unroll
      for (int j = 0; j < 4; ++j) {
        *(float4*)ks4v[j] = *(const float4*)(kL + (saD + j) * PCH + d);
        *(float4*)cs4v[j] = *(const float4*)(cgL + (saD + j) * PCH + d);
      }
#pragma unroll
      for (int i = 0; i < 4; ++i) {
        float kt4[4], qt4[4], ct4[4];
        *(float4*)kt4 = *(const float4*)(kL + (taD + i) * PCH + d);
        *(float4*)qt4 = *(const float4*)(qL + (taD + i) * PCH + d);
        *(float4*)ct4 = *(const float4*)(cgL + (taD + i) * PCH + d);
#pragma unroll
        for (int j = 0; j < 4; ++j)
#pragma unroll
          for (int dd = 0; dd < 4; ++dd) {
            float diff = ct4[dd] - cs4v[j][dd];
            float e = __expf(fminf(diff, 0.f));
            float m = e * ks4v[j][dd];
            accA[i * 4 + j] += kt4[dd] * m;
            accW[i * 4 + j] += qt4[dd] * m;
          }
      }
    }
    // quad-local reduction over the 4 d-splits (lanes 4L+dh, same wave)
#pragma unroll
    for (int i = 0; i < 16; ++i) {
      accA[i] += __shfl_xor(accA[i], 1);
      accA[i] += __shfl_xor(accA[i], 2);
      accW[i] += __shfl_xor(accW[i], 1);
      accW[i] += __shfl_xor(accW[i], 2);
    }
    if (dh == 0) {
      size_t wb = (size_t)bid * 4096;
#pragma unroll
      for (int i = 0; i < 4; ++i)
#pragma unroll
        for (int j = 0; j < 4; ++j) {
          int t = taD + i, s = saD + j;
          if (s < t) ML[t * MP + s] = bL[t] * accA[i * 4 + j];
          float wv = (s <= t) ? accW[i * 4 + j] : 0.f;
          w_g[wb + (size_t)(s >> 3) * 512 + t * 8 + (s & 7)] = wv;
        }
    }
  }
  __syncthreads();

  // (e) N = (I + B A)^-1, stored transposed in NT
  for (int i = tid; i < 4352; i += 1024) NT[i] = 0.f;
  __syncthreads();
  if (tid < 64) {
    int b4 = tid >> 4, j = tid & 15, bo = b4 * 16;
    NT[(bo + j) * MP + bo + j] = 1.f;
    for (int t = j + 1; t < 16; ++t) {
      float s = 0.f;
      for (int sx = j; sx < t; ++sx)
        s += ML[(bo + t) * MP + bo + sx] * NT[(bo + j) * MP + bo + sx];
      NT[(bo + j) * MP + bo + t] = -s;
    }
  }
  __syncthreads();
  for (int lev = 1; lev <= 3; ++lev) {
    int nb = 4 - lev;
    for (int idx = tid; idx < nb * 256; idx += 1024) {
      int J = idx >> 8, I = J + lev;
      int i = (idx >> 4) & 15, j = idx & 15;
      float s = 0.f;
      for (int P = J; P < I; ++P)
#pragma unroll 4
        for (int p = 0; p < 16; ++p)
          s += ML[(16 * I + i) * MP + 16 * P + p] * NT[(16 * J + j) * MP + 16 * P + p];
      GB[J * 256 + i * 16 + j] = s;
    }
    __syncthreads();
    for (int idx = tid; idx < nb * 256; idx += 1024) {
      int J = idx >> 8, I = J + lev;
      int i = (idx >> 4) & 15, j = idx & 15;
      float s = 0.f;
#pragma unroll 4
      for (int p = 0; p < 16; ++p)
        s += NT[(16 * I + p) * MP + 16 * I + i] * GB[J * 256 + p * 16 + j];
      NT[(16 * J + j) * MP + 16 * I + i] = -s;
    }
    __syncthreads();
  }

  // (f) RHS_z = b * k * e^cg ; Z = N * RHS_z  (tiled store)
  {
    int tW = tid >> 4, g = tid & 15;
    float b = bL[tW];
#pragma unroll
    for (int i = 0; i < 2; ++i) {
      int d = g * 8 + 4 * i;
      float4 kv = *(const float4*)(kL + tW * PCH + d);
      float4 cg4 = *(const float4*)(cgL + tW * PCH + d);
      float4 r;
      r.x = b * kv.x * __expf(cg4.x); r.y = b * kv.y * __expf(cg4.y);
      r.z = b * kv.z * __expf(cg4.z); r.w = b * kv.w * __expf(cg4.w);
      *(float4*)(qL + tW * PCH + d) = r;
    }
  }
  __syncthreads();
  {
    int t2 = tid >> 5, c4 = tid & 31;
    float acc[2][4];
#pragma unroll
    for (int i = 0; i < 2; ++i)
#pragma unroll
      for (int j = 0; j < 4; ++j) acc[i][j] = 0.f;
    for (int s = 0; s < 64; ++s) {
      float2 nv = *(const float2*)(NT + s * MP + t2 * 2);
      float rv[4];
      *(float4*)rv = *(const float4*)(qL + s * PCH + c4 * 4);
#pragma unroll
      for (int j = 0; j < 4; ++j) {
        acc[0][j] += nv.x * rv[j];
        acc[1][j] += nv.y * rv[j];
      }
    }
    size_t zb = (size_t)bid * 8192 + (size_t)(c4 >> 2) * 1024 + (c4 & 3) * 4;
#pragma unroll
    for (int i = 0; i < 2; ++i) {
      float4 o; o.x = acc[i][0]; o.y = acc[i][1]; o.z = acc[i][2]; o.w = acc[i][3];
      *(float4*)(z_g + zb + (size_t)(t2 * 2 + i) * 16) = o;
    }
  }
  __syncthreads();

  // (g) RHS_v = b * silu(conv(v)) ; U0 = N * RHS_v (natural store)
  for (int it = 0; it < 8; ++it) {
    int cell = tid + (it << 10);
    int d = cell & 127, t = cell >> 7;
    int ch = 2 * CH1 + h * HD + d;
    float4 w4 = ((const float4*)cw)[ch];
    int rbase = t0 + t - 3;
    float acc;
    if (rbase >= 0) {
      const float* mp = mixed + (size_t)rbase * CH3 + ch;
      acc = mp[0] * w4.x + mp[CH3] * w4.y + mp[2 * CH3] * w4.z + mp[3 * CH3] * w4.w;
    } else {
      acc = 0.f;
      if (rbase + 0 >= 0) acc += mixed[(size_t)(rbase + 0) * CH3 + ch] * w4.x;
      if (rbase + 1 >= 0) acc += mixed[(size_t)(rbase + 1) * CH3 + ch] * w4.y;
      if (rbase + 2 >= 0) acc += mixed[(size_t)(rbase + 2) * CH3 + ch] * w4.z;
      acc += mixed[(size_t)(rbase + 3) * CH3 + ch] * w4.w;
    }
    acc = acc / (1.f + __expf(-acc));
    qL[t * PCH + d] = bL[t] * acc;
  }
  __syncthreads();
  {
    int t2 = tid >> 5, c4 = tid & 31;
    float acc[2][4];
#pragma unroll
    for (int i = 0; i < 2; ++i)
#pragma unroll
      for (int j = 0; j < 4; ++j) acc[i][j] = 0.f;
    for (int s = 0; s < 64; ++s) {
      float2 nv = *(const float2*)(NT + s * MP + t2 * 2);
      float rv[4];
      *(float4*)rv = *(const float4*)(qL + s * PCH + c4 * 4);
#pragma unroll
      for (int j = 0; j < 4; ++j) {
        acc[0][j] += nv.x * rv[j];
        acc[1][j] += nv.y * rv[j];
      }
    }
#pragma unroll
    for (int i = 0; i < 2; ++i) {
      size_t ob = ((size_t)(t0 + t2 * 2 + i) * NH + h) * HD + c4 * 4;
      float4 o; o.x = acc[i][0]; o.y = acc[i][1]; o.z = acc[i][2]; o.w = acc[i][3];
      *(float4*)(u0_g + ob) = o;
    }
  }
}

// ---------------------------------------------------------------------------
// Kernel B v5 (unchanged from R4 -- verified): grid 256, 3 barriers/chunk,
// concurrent wave-split phases, P4 deferred one chunk.
// ---------------------------------------------------------------------------
#define PT 68
#define PG 544   // 8 j * 68

__global__ __launch_bounds__(512, 2)
void kda_scan3(const float* __restrict__ qt_g, const float* __restrict__ kbt_g,
               const float* __restrict__ u0_g, const float* __restrict__ z_g,
               const float* __restrict__ w_g, const float* __restrict__ ecg_g,
               float* __restrict__ out, float* __restrict__ slabs) {
  __shared__ float Tp[4352], Op[4352];   // [8g][8j][68]
  __shared__ float Wp[2176];             // [4g][8j][68]
  __shared__ float Sl[1536];             // [128 k][12 pitch] (8 j used)
  __shared__ float Un[512];              // [64 t][8 j]
  __shared__ float Ut[544];              // [8 j][68]
  (void)slabs;
  const int tid = threadIdx.x;
  const int bid = blockIdx.x;
  const int h = bid & 15, vg = bid >> 4;
  const int gA = tid >> 6, tA = tid & 63;
  const int tH = (tid & 255) >> 2;        // 0..63 (both half-sets)
  const int jH = (tid & 3) << 1;          // 0,2,4,6 (pairs jH, jH+1)
  const int kC = tid & 127;               // lo half: S row
  const int jq = ((tid >> 7) & 1) << 2;   // lo half: j-quad 0 or 4
  const int gB = (tid >> 6) & 3;          // hi half: s-group 0..3

  for (int i = tid; i < 1536; i += 512) Sl[i] = 0.f;
  __syncthreads();

  float OsA = 0.f, OsB = 0.f;            // hi half: deferred O1 sums

  for (int c = 0; c < NC; ++c) {
    const int ch = c * 16 + h;
    // ---- loads for chunk c, issued up front ----
    float z[16], q[16];
    {
      const float* zb = z_g + (size_t)ch * 8192 + gA * 1024 + tA * 16;
      const float* qb = qt_g + (size_t)ch * 8192 + gA * 1024 + tA * 16;
#pragma unroll
      for (int i = 0; i < 4; ++i) {
        *(float4*)(z + 4 * i) = *(const float4*)(zb + 4 * i);
        *(float4*)(q + 4 * i) = *(const float4*)(qb + 4 * i);
      }
    }
    float w16[16];   // hi: W[t=tA][s = gB*16 .. +16]
    float u0a = 0.f, u0b = 0.f;
    float kv[64], eC = 0.f;
    if (tid < 256) {
      const float* kb = kbt_g + (size_t)ch * 8192 + (size_t)kC * 64;
#pragma unroll
      for (int t4 = 0; t4 < 16; ++t4)
        *(float4*)(kv + 4 * t4) = *(const float4*)(kb + 4 * t4);
      eC = ecg_g[(size_t)ch * 128 + kC];
      const float* ub = u0_g + ((size_t)(c * 64 + tH) * NH + h) * HD + vg * 8 + jH;
      u0a = ub[0]; u0b = ub[1];
    } else {
      const float* wb = w_g + (size_t)ch * 4096 + (size_t)(gB * 2) * 512 + tA * 8;
      *(float4*)w16       = *(const float4*)(wb);
      *(float4*)(w16 + 4) = *(const float4*)(wb + 4);
      *(float4*)(w16 + 8)  = *(const float4*)(wb + 512);
      *(float4*)(w16 + 12) = *(const float4*)(wb + 516);
    }

    // ---- phase1: [hi: prev-chunk P4] || [all: P1 partials] ----
    if (tid >= 256 && c > 0) {
      float O2a = 0.f, O2b = 0.f;
#pragma unroll
      for (int g = 0; g < 4; ++g) {
        O2a += Wp[g * PG + jH * PT + tH];
        O2b += Wp[g * PG + (jH + 1) * PT + tH];
      }
      float* ob = out + ((size_t)((c - 1) * 64 + tH) * NH + h) * HD + vg * 8 + jH;
      ob[0] = OsA + O2a; ob[1] = OsB + O2b;
    }
    {
      float Ta[8], Oa[8];
#pragma unroll
      for (int j = 0; j < 8; ++j) { Ta[j] = 0.f; Oa[j] = 0.f; }
#pragma unroll
      for (int dd = 0; dd < 16; ++dd) {
        float s8[8];
        const float* sr = Sl + (gA * 16 + dd) * 12;
        *(float4*)s8 = *(const float4*)(sr);
        *(float4*)(s8 + 4) = *(const float4*)(sr + 4);
        float zz = z[dd], qq = q[dd];
#pragma unroll
        for (int j = 0; j < 8; ++j) { Ta[j] += zz * s8[j]; Oa[j] += qq * s8[j]; }
      }
#pragma unroll
      for (int j = 0; j < 8; ++j) {
        Tp[gA * PG + j * PT + tA] = Ta[j];
        Op[gA * PG + j * PT + tA] = Oa[j];
      }
    }
    __syncthreads();

    // ---- phase2: [lo: T-reduce -> U] || [hi: O-reduce -> regs] ----
    if (tid < 256) {
      float Tsa = 0.f, Tsb = 0.f;
#pragma unroll
      for (int g = 0; g < 8; ++g) {
        Tsa += Tp[g * PG + jH * PT + tH];
        Tsb += Tp[g * PG + (jH + 1) * PT + tH];
      }
      float Ua = u0a - Tsa, Ub = u0b - Tsb;
      Un[tH * 8 + jH] = Ua; Un[tH * 8 + jH + 1] = Ub;
      Ut[jH * PT + tH] = Ua; Ut[(jH + 1) * PT + tH] = Ub;
    } else {
      float Os1 = 0.f, Os2 = 0.f;
#pragma unroll
      for (int g = 0; g < 8; ++g) {
        Os1 += Op[g * PG + jH * PT + tH];
        Os2 += Op[g * PG + (jH + 1) * PT + tH];
      }
      OsA = Os1; OsB = Os2;
    }
    __syncthreads();

    // ---- phase3: [lo: P5 S-update] || [hi: P3 W*U partials -> Wp] ----
    if (tid < 256) {
      float a0 = 0.f, a1 = 0.f, a2 = 0.f, a3 = 0.f;
      const float* u0r = Ut + (jq + 0) * PT;
      const float* u1r = Ut + (jq + 1) * PT;
      const float* u2r = Ut + (jq + 2) * PT;
      const float* u3r = Ut + (jq + 3) * PT;
#pragma unroll
      for (int t4 = 0; t4 < 16; ++t4) {
        float k0 = kv[4 * t4], k1 = kv[4 * t4 + 1], k2 = kv[4 * t4 + 2], k3 = kv[4 * t4 + 3];
        float4 ua = *(const float4*)(u0r + 4 * t4);
        float4 ub = *(const float4*)(u1r + 4 * t4);
        float4 uc = *(const float4*)(u2r + 4 * t4);
        float4 ud = *(const float4*)(u3r + 4 * t4);
        a0 += k0 * ua.x + k1 * ua.y + k2 * ua.z + k3 * ua.w;
        a1 += k0 * ub.x + k1 * ub.y + k2 * ub.z + k3 * ub.w;
        a2 += k0 * uc.x + k1 * uc.y + k2 * uc.z + k3 * uc.w;
        a3 += k0 * ud.x + k1 * ud.y + k2 * ud.z + k3 * ud.w;
      }
      float* sp = Sl + kC * 12 + jq;
      float4 s = *(float4*)sp;
      s.x = eC * s.x + a0; s.y = eC * s.y + a1;
      s.z = eC * s.z + a2; s.w = eC * s.w + a3;
      *(float4*)sp = s;
    } else {
      float Wa[8];
#pragma unroll
      for (int j = 0; j < 8; ++j) Wa[j] = 0.f;
#pragma unroll
      for (int sp = 0; sp < 16; ++sp) {
        const float* ur = Un + (gB * 16 + sp) * 8;
        float u8[8];
        *(float4*)u8 = *(const float4*)(ur);
        *(float4*)(u8 + 4) = *(const float4*)(ur + 4);
        float wv = w16[sp];
#pragma unroll
        for (int j = 0; j < 8; ++j) Wa[j] += wv * u8[j];
      }
#pragma unroll
      for (int j = 0; j < 8; ++j) Wp[gB * PG + j * PT + tA] = Wa[j];
    }
    __syncthreads();
  }

  // ---- epilogue: final P4 for chunk NC-1 ----
  if (tid >= 256) {
    float O2a = 0.f, O2b = 0.f;
#pragma unroll
    for (int g = 0; g < 4; ++g) {
      O2a += Wp[g * PG + jH * PT + tH];
      O2b += Wp[g * PG + (jH + 1) * PT + tH];
    }
    float* ob = out + ((size_t)((NC - 1) * 64 + tH) * NH + h) * HD + vg * 8 + jH;
    ob[0] = OsA + O2a; ob[1] = OsB + O2b;
  }
}

// ---------------------------------------------------------------------------
extern "C" void kernel_launch(void* const* d_in, const int* in_sizes, int n_in,
                              void* d_out, int out_size, void* d_ws, size_t ws_size,
                              hipStream_t stream) {
  const float* mixed = (const float*)d_in[0];
  const float* fg    = (const float*)d_in[1];
  const float* beta  = (const float*)d_in[2];
  const float* cw    = (const float*)d_in[3];
  const float* dtb   = (const float*)d_in[4];
  const float* alog  = (const float*)d_in[5];
  float* ws = (float*)d_ws;
  float* qt_g  = ws + QT_OFF;
  float* kbt_g = ws + KBT_OFF;
  float* u0_g  = ws + U0_OFF;
  float* z_g   = ws + Z_OFF;
  float* w_g   = ws + W_OFF;
  float* ecg_g = ws + ECG_OFF;
  float* slabs = ws + SLAB_OFF;

  hipLaunchKernelGGL(kda_chunk, dim3(NC * NH), dim3(1024), 0, stream,
                     mixed, fg, beta, cw, dtb, alog,
                     qt_g, kbt_g, u0_g, z_g, w_g, ecg_g);
  hipLaunchKernelGGL(kda_scan3, dim3(256), dim3(512), 0, stream,
                     qt_g, kbt_g, u0_g, z_g, w_g, ecg_g, (float*)d_out, slabs);
  (void)in_sizes; (void)n_in; (void)out_size; (void)ws_size;
}